// Round 2
// baseline (1709.041 us; speedup 1.0000x reference)
//
#include <hip/hip_runtime.h>
#include <hip/hip_bf16.h>
#include <math.h>

typedef _Float16 f16;
typedef __attribute__((ext_vector_type(8))) _Float16 f16x8;
typedef __attribute__((ext_vector_type(4))) float f32x4;

#define TOKENS 65536
#define D_ 512
#define F_ 1024
#define E_ 8
#define DT_ 16
#define TEMP_ 1.0f

// ---- workspace layout (bytes) ----
#define OFF_CNT   0
#define OFF_IMP   64
#define OFF_TOK   4096
#define OFF_GATE  (OFF_TOK  + E_*TOKENS*4)   // +2 MB
#define OFF_W1T   (OFF_GATE + E_*TOKENS*4)   // +2 MB
#define OFF_W2T   (OFF_W1T  + E_*F_*D_*2)    // +8 MB
// total = OFF_W2T + 8 MB  ~= 21 MB

// ---------------------------------------------------------------------------
// Transpose + f32->f16 convert: src [E][R][C] f32 -> dst [E][C][R] f16
// ---------------------------------------------------------------------------
__global__ __launch_bounds__(256) void k_transpose(const float* __restrict__ src,
                                                   f16* __restrict__ dst, int R, int C)
{
  __shared__ float tile[32][33];
  int e = blockIdx.z;
  const float* s = src + (size_t)e * R * C;
  f16* d = dst + (size_t)e * R * C;
  int c0 = blockIdx.x * 32, r0 = blockIdx.y * 32;
  int tx = threadIdx.x, ty = threadIdx.y;   // 32 x 8
  #pragma unroll
  for (int i = 0; i < 32; i += 8)
    tile[ty + i][tx] = s[(size_t)(r0 + ty + i) * C + c0 + tx];
  __syncthreads();
  #pragma unroll
  for (int i = 0; i < 32; i += 8)
    d[(size_t)(c0 + ty + i) * R + r0 + tx] = (f16)tile[tx][ty + i];
}

// ---------------------------------------------------------------------------
// Router: fp32 logits, top-2 + gates, aux-loss partials, dispatch lists.
// ---------------------------------------------------------------------------
__global__ __launch_bounds__(256) void k_router(
    const float* __restrict__ x, const float* __restrict__ z, const float* __restrict__ tau,
    const float* __restrict__ Wr, const float* __restrict__ br,
    int* __restrict__ gcnt, float* __restrict__ gimp,
    int* __restrict__ tokrec, float* __restrict__ gaterec)
{
  __shared__ float zlog[E_];
  __shared__ float stau;
  __shared__ int   recI[128];
  __shared__ float rg0[128], rg1[128];
  __shared__ int   pos0[128], pos1[128];
  __shared__ int   lcnt[E_], lbase[E_];
  __shared__ float limp[E_];

  int tid = threadIdx.x, lane = tid & 63, w = tid >> 6;
  int t0 = blockIdx.x * 128;
  int b = t0 >> 11;

  if (tid < E_) {
    float s = br[tid];
    #pragma unroll
    for (int dt = 0; dt < DT_; ++dt) s += z[b * DT_ + dt] * Wr[(D_ + dt) * E_ + tid];
    zlog[tid] = s;
    lcnt[tid] = 0; limp[tid] = 0.f;
  }
  if (tid == 0) stau = TEMP_ * tau[b];

  float wreg[8][8];
  const float* wp = Wr + lane * 64;
  #pragma unroll
  for (int j = 0; j < 8; ++j) {
    f32x4 a = *(const f32x4*)(wp + j * 8);
    f32x4 c = *(const f32x4*)(wp + j * 8 + 4);
    wreg[j][0]=a[0]; wreg[j][1]=a[1]; wreg[j][2]=a[2]; wreg[j][3]=a[3];
    wreg[j][4]=c[0]; wreg[j][5]=c[1]; wreg[j][6]=c[2]; wreg[j][7]=c[3];
  }
  __syncthreads();
  float tv = stau;
  float imp[E_];
  #pragma unroll
  for (int e2 = 0; e2 < E_; ++e2) imp[e2] = 0.f;

  for (int i = 0; i < 32; ++i) {
    int li = w * 32 + i;
    int t = t0 + li;
    const float* xr = x + (size_t)t * D_ + lane * 8;
    f32x4 xa = *(const f32x4*)xr;
    f32x4 xb = *(const f32x4*)(xr + 4);
    float v[E_];
    #pragma unroll
    for (int e2 = 0; e2 < E_; ++e2)
      v[e2] = xa[0]*wreg[0][e2] + xa[1]*wreg[1][e2] + xa[2]*wreg[2][e2] + xa[3]*wreg[3][e2]
            + xb[0]*wreg[4][e2] + xb[1]*wreg[5][e2] + xb[2]*wreg[6][e2] + xb[3]*wreg[7][e2];
    #pragma unroll
    for (int s = 0; s < 6; ++s) {
      #pragma unroll
      for (int e2 = 0; e2 < E_; ++e2) v[e2] += __shfl_xor(v[e2], 1 << s, 64);
    }
    if (lane == 0) {
      #pragma unroll
      for (int e2 = 0; e2 < E_; ++e2) v[e2] = (v[e2] + zlog[e2]) / tv;
      int i0 = 0; float b0v = v[0];
      #pragma unroll
      for (int e2 = 1; e2 < E_; ++e2) if (v[e2] > b0v) { b0v = v[e2]; i0 = e2; }
      int i1 = -1; float b1v = -3.4e38f;
      #pragma unroll
      for (int e2 = 0; e2 < E_; ++e2) if (e2 != i0 && v[e2] > b1v) { b1v = v[e2]; i1 = e2; }
      float ee = expf(b1v - b0v);
      float g0 = 1.f / (1.f + ee);
      recI[li] = i0 | (i1 << 4);
      rg0[li] = g0; rg1[li] = ee * g0;
      float ssum = 0.f, pe[E_];
      #pragma unroll
      for (int e2 = 0; e2 < E_; ++e2) { pe[e2] = expf(v[e2] - b0v); ssum += pe[e2]; }
      float inv = 1.f / ssum;
      #pragma unroll
      for (int e2 = 0; e2 < E_; ++e2) imp[e2] += pe[e2] * inv;
    }
  }
  if (lane == 0) {
    #pragma unroll
    for (int e2 = 0; e2 < E_; ++e2) atomicAdd(&limp[e2], imp[e2]);
  }
  __syncthreads();
  if (tid < 128) {
    int r = recI[tid], i0 = r & 15, i1 = r >> 4;
    pos0[tid] = atomicAdd(&lcnt[i0], 1);
    pos1[tid] = atomicAdd(&lcnt[i1], 1);
  }
  __syncthreads();
  if (tid < E_) {
    lbase[tid] = atomicAdd(&gcnt[tid], lcnt[tid]);
    atomicAdd(&gimp[tid], limp[tid]);
  }
  __syncthreads();
  if (tid < 128) {
    int r = recI[tid], i0 = r & 15, i1 = r >> 4;
    int t = t0 + tid;
    int o0 = i0 * TOKENS + lbase[i0] + pos0[tid];
    int o1 = i1 * TOKENS + lbase[i1] + pos1[tid];
    tokrec[o0] = t; gaterec[o0] = rg0[tid];
    tokrec[o1] = t; gaterec[o1] = rg1[tid];
  }
}

// ---------------------------------------------------------------------------
// Fused expert MLP. Expert = blockIdx & 7 -> XCD-pinned (blockIdx round-robins
// across the 8 XCDs), so each XCD's 4MB L2 holds exactly one expert's 2MB of
// f16 weights. Weight loads clustered into register arrays for latency
// amortization (one vmcnt wait per ~8 MFMAs).
// ---------------------------------------------------------------------------
__global__ __launch_bounds__(512, 4) void k_mlp(
    const float* __restrict__ x,
    const f16* __restrict__ W1t, const float* __restrict__ b1,
    const f16* __restrict__ W2t, const float* __restrict__ b2,
    const int* __restrict__ gcnt, const int* __restrict__ tokrec,
    const float* __restrict__ gaterec, float* __restrict__ y)
{
  int e    = blockIdx.x & 7;       // XCD pin: same expert -> same XCD L2
  int tile = blockIdx.x >> 3;
  int cnt  = gcnt[e];
  int start = tile * 64;
  if (start >= cnt) return;

  __shared__ f16   xs[64 * 512];   // 64 KB, XOR-swizzled
  __shared__ f16   hs[64 * 64];    // 8 KB, XOR-swizzled
  __shared__ int   stok[64];
  __shared__ float sgate[64];

  int tid = threadIdx.x, lane = tid & 63, w = tid >> 6;

  if (tid < 64) {
    int idx = start + tid;
    stok[tid]  = (idx < cnt) ? tokrec[e * TOKENS + idx] : -1;
    sgate[tid] = (idx < cnt) ? gaterec[e * TOKENS + idx] : 0.f;
  }
  __syncthreads();

  // gather + convert x rows into LDS
  for (int r = w; r < 64; r += 8) {
    int tk = stok[r];
    f32x4 a = {0.f,0.f,0.f,0.f}, bv = {0.f,0.f,0.f,0.f};
    if (tk >= 0) {
      const float* p = x + (size_t)tk * D_ + lane * 8;
      a  = *(const f32x4*)p;
      bv = *(const f32x4*)(p + 4);
    }
    f16x8 pk;
    pk[0]=(f16)a[0];  pk[1]=(f16)a[1];  pk[2]=(f16)a[2];  pk[3]=(f16)a[3];
    pk[4]=(f16)bv[0]; pk[5]=(f16)bv[1]; pk[6]=(f16)bv[2]; pk[7]=(f16)bv[3];
    int off = (r * 1024 + lane * 16) ^ ((r & 7) << 4);
    *(f16x8*)((char*)xs + off) = pk;
  }
  __syncthreads();

  f32x4 yacc[4][4];
  #pragma unroll
  for (int mt = 0; mt < 4; ++mt)
    #pragma unroll
    for (int nt = 0; nt < 4; ++nt) {
      yacc[mt][nt][0]=0.f; yacc[mt][nt][1]=0.f; yacc[mt][nt][2]=0.f; yacc[mt][nt][3]=0.f;
    }

  int rb  = (w & 3) * 16;    // stage-A token-row base
  int cbA = (w >> 2) * 32;   // stage-A F-col base within chunk
  int cb2 = w * 64;          // stage-B D-col base
  int l15 = lane & 15;
  int lk8 = (lane >> 4) * 8;
  const f16* w2p = W2t + (size_t)e * D_ * F_;

  for (int it = 0; it < 16; ++it) {
    int fc = it * 64;
    // hoist b1 loads so their latency hides under stage A
    float b1v0 = b1[e * F_ + fc + cbA + l15];
    float b1v1 = b1[e * F_ + fc + cbA + 16 + l15];

    // ---- stage A: H[64 x 64] = x_tile @ W1t-chunk ----
    f32x4 h0 = {0.f,0.f,0.f,0.f}, h1 = {0.f,0.f,0.f,0.f};
    const f16* w1p = W1t + ((size_t)e * F_ + fc + cbA) * D_;
    #pragma unroll
    for (int kg = 0; kg < 4; ++kg) {
      // cluster 8 weight loads (4 ks-steps) -> one amortized vmcnt wait
      f16x8 wb[8];
      #pragma unroll
      for (int j = 0; j < 4; ++j) {
        int k0 = (kg * 4 + j) * 32 + lk8;
        wb[j]     = *(const f16x8*)(w1p + (size_t)l15 * D_ + k0);
        wb[j + 4] = *(const f16x8*)(w1p + (size_t)(l15 + 16) * D_ + k0);
      }
      #pragma unroll
      for (int j = 0; j < 4; ++j) {
        int k0 = (kg * 4 + j) * 32 + lk8;
        int arow = rb + l15;
        int aoff = (arow * 1024 + k0 * 2) ^ ((arow & 7) << 4);
        f16x8 af = *(const f16x8*)((const char*)xs + aoff);
        h0 = __builtin_amdgcn_mfma_f32_16x16x32_f16(af, wb[j],     h0, 0, 0, 0);
        h1 = __builtin_amdgcn_mfma_f32_16x16x32_f16(af, wb[j + 4], h1, 0, 0, 0);
      }
    }
    __syncthreads();   // everyone done reading hs from previous iter
    {
      #pragma unroll
      for (int rg = 0; rg < 4; ++rg) {
        int row = rb + ((lane >> 4) << 2) + rg;
        float v0 = h0[rg] + b1v0;
        float v1 = h1[rg] + b1v1;
        v0 = 0.5f * v0 * (1.f + erff(v0 * 0.70710678118654752f));
        v1 = 0.5f * v1 * (1.f + erff(v1 * 0.70710678118654752f));
        int o0 = (row * 128 + (cbA + l15) * 2)      ^ ((row & 7) << 4);
        int o1 = (row * 128 + (cbA + 16 + l15) * 2) ^ ((row & 7) << 4);
        *(f16*)((char*)hs + o0) = (f16)v0;
        *(f16*)((char*)hs + o1) = (f16)v1;
      }
    }
    __syncthreads();   // hs ready
    // ---- stage B: yacc += H @ W2t-chunk ----
    // cluster all 8 W2 fragment loads for this iter up front
    f16x8 wb2[8];
    #pragma unroll
    for (int ks = 0; ks < 2; ++ks)
      #pragma unroll
      for (int nt = 0; nt < 4; ++nt)
        wb2[ks * 4 + nt] = *(const f16x8*)(w2p + (size_t)(cb2 + nt * 16 + l15) * F_ + fc + ks * 32 + lk8);
    #pragma unroll
    for (int ks = 0; ks < 2; ++ks) {
      int k0 = ks * 32 + lk8;
      f16x8 afr[4];
      #pragma unroll
      for (int mt = 0; mt < 4; ++mt) {
        int arow = mt * 16 + l15;
        int aoff = (arow * 128 + k0 * 2) ^ ((arow & 7) << 4);
        afr[mt] = *(const f16x8*)((const char*)hs + aoff);
      }
      #pragma unroll
      for (int nt = 0; nt < 4; ++nt) {
        #pragma unroll
        for (int mt = 0; mt < 4; ++mt)
          yacc[mt][nt] = __builtin_amdgcn_mfma_f32_16x16x32_f16(afr[mt], wb2[ks * 4 + nt], yacc[mt][nt], 0, 0, 0);
      }
    }
  }

  // epilogue: y[token] += gate * (acc + b2)
  float b2s[4];
  #pragma unroll
  for (int nt = 0; nt < 4; ++nt) b2s[nt] = b2[e * D_ + cb2 + nt * 16 + l15];
  #pragma unroll
  for (int mt = 0; mt < 4; ++mt) {
    #pragma unroll
    for (int rg = 0; rg < 4; ++rg) {
      int row = mt * 16 + ((lane >> 4) << 2) + rg;
      int tk = stok[row];
      if (tk < 0) continue;
      float g = sgate[row];
      float* yp = y + (size_t)tk * D_ + cb2 + l15;
      #pragma unroll
      for (int nt = 0; nt < 4; ++nt)
        atomicAdd(yp + nt * 16, g * (yacc[mt][nt][rg] + b2s[nt]));
    }
  }
}

// ---------------------------------------------------------------------------
__global__ void k_aux(const int* __restrict__ gcnt, const float* __restrict__ gimp,
                      float* __restrict__ outp)
{
  if (threadIdx.x == 0) {
    float a = 0.f;
    for (int e2 = 0; e2 < E_; ++e2)
      a += ((float)gcnt[e2] * (1.f / 65536.f)) * (gimp[e2] * (1.f / 65536.f));
    outp[0] = (float)E_ * a;
  }
}

extern "C" void kernel_launch(void* const* d_in, const int* in_sizes, int n_in,
                              void* d_out, int out_size, void* d_ws, size_t ws_size,
                              hipStream_t stream)
{
  const float* x   = (const float*)d_in[0];
  const float* z   = (const float*)d_in[1];
  const float* tau = (const float*)d_in[2];
  const float* Wr  = (const float*)d_in[3];
  const float* br  = (const float*)d_in[4];
  const float* W1  = (const float*)d_in[5];
  const float* b1  = (const float*)d_in[6];
  const float* W2  = (const float*)d_in[7];
  const float* b2  = (const float*)d_in[8];
  float* out = (float*)d_out;
  char*  ws  = (char*)d_ws;

  int*   gcnt    = (int*)  (ws + OFF_CNT);
  float* gimp    = (float*)(ws + OFF_IMP);
  int*   tokrec  = (int*)  (ws + OFF_TOK);
  float* gaterec = (float*)(ws + OFF_GATE);
  f16*   W1t     = (f16*)  (ws + OFF_W1T);
  f16*   W2t     = (f16*)  (ws + OFF_W2T);

  hipMemsetAsync(ws, 0, 4096, stream);
  hipMemsetAsync(d_out, 0, (size_t)out_size * 4, stream);

  dim3 tb(32, 8);
  k_transpose<<<dim3(F_/32, D_/32, E_), tb, 0, stream>>>(W1, W1t, D_, F_); // [E][F][D]
  k_transpose<<<dim3(D_/32, F_/32, E_), tb, 0, stream>>>(W2, W2t, F_, D_); // [E][D][F]

  k_router<<<TOKENS / 128, 256, 0, stream>>>(x, z, tau, Wr, br, gcnt, gimp, tokrec, gaterec);

  k_mlp<<<E_ * 1024, 512, 0, stream>>>(x, W1t, b1, W2t, b2, gcnt, tokrec, gaterec, out);

  k_aux<<<1, 64, 0, stream>>>(gcnt, gimp, out + (size_t)TOKENS * D_);
}

// Round 3
// 1096.452 us; speedup vs baseline: 1.5587x; 1.5587x over previous
//
#include <hip/hip_runtime.h>
#include <hip/hip_bf16.h>
#include <math.h>

typedef _Float16 f16;
typedef __attribute__((ext_vector_type(8))) _Float16 f16x8;
typedef __attribute__((ext_vector_type(4))) float f32x4;

#define TOKENS 65536
#define D_ 512
#define F_ 1024
#define E_ 8
#define DT_ 16
#define TEMP_ 1.0f

// ---- workspace layout (bytes) ----
#define OFF_CNT   0                              // 8 ints: per-expert counts
#define OFF_SBASE 64                             // 8 ints: exclusive scan of counts
#define OFF_IMP   128                            // 8 floats: importance partials
#define OFF_SLOT0 4096                           // per-token seg-slot of rank-0 expert
#define OFF_SLOT1 (OFF_SLOT0 + TOKENS*4)
#define OFF_TOK   (OFF_SLOT1 + TOKENS*4)         // segmented token lists [E][TOKENS]
#define OFF_GATE  (OFF_TOK  + E_*TOKENS*4)
#define OFF_W1P   (OFF_GATE + E_*TOKENS*4)       // packed W1, 8 MB
#define OFF_W2P   (OFF_W1P  + E_*F_*D_*2)        // packed W2, 8 MB
#define OFF_REC   (OFF_W2P  + E_*F_*D_*2)        // f16 expert-output records, 134 MB
#define REC_BYTES ((size_t)(2*TOKENS) * D_ * 2)

// ---------------------------------------------------------------------------
// Pack src [E][R][C] f32 (R = K-dim, C = N-dim) into MFMA-B-fragment order:
// dst [E][C/16 coltile][R/32 kstep][64 lane][8 f16], where lane l of tile
// (ct,ks) holds src[e][ks*32 + (l>>4)*8 + j][ct*16 + (l&15)].
// A wave's fragment load becomes one contiguous 1KB burst (fully coalesced).
// ---------------------------------------------------------------------------
__global__ __launch_bounds__(256) void k_pack(const float* __restrict__ src,
                                              f16* __restrict__ dst, int R, int C)
{
  int e = blockIdx.y, ct = blockIdx.x;
  int tid = threadIdx.x;
  int c = tid & 15, r8 = tid >> 4;   // 16 cols x 16 row-groups (of 8)
  const float* s = src + (size_t)e * R * C + (size_t)ct * 16 + c;
  f16* d = dst + ((size_t)e * (C / 16) + ct) * (size_t)(R / 32) * 512;
  int passes = R / 128;
  for (int p = 0; p < passes; ++p) {
    int k0 = (p * 16 + r8) * 8;
    int ks = k0 >> 5, lg = (k0 >> 3) & 3;
    f16x8 v;
    #pragma unroll
    for (int j = 0; j < 8; ++j) v[j] = (f16)s[(size_t)(k0 + j) * C];
    *(f16x8*)(d + (size_t)ks * 512 + (size_t)(c + 16 * lg) * 8) = v;
  }
}

// ---------------------------------------------------------------------------
// Router: fp32 logits, top-2 + gates, aux partials, dispatch lists + per-token
// slot records (for the atomic-free combine pass).
// ---------------------------------------------------------------------------
__global__ __launch_bounds__(256) void k_router(
    const float* __restrict__ x, const float* __restrict__ z, const float* __restrict__ tau,
    const float* __restrict__ Wr, const float* __restrict__ br,
    int* __restrict__ gcnt, float* __restrict__ gimp,
    int* __restrict__ tokrec, float* __restrict__ gaterec,
    int* __restrict__ slot0, int* __restrict__ slot1)
{
  __shared__ float zlog[E_];
  __shared__ float stau;
  __shared__ int   recI[128];
  __shared__ float rg0[128], rg1[128];
  __shared__ int   pos0[128], pos1[128];
  __shared__ int   lcnt[E_], lbase[E_];
  __shared__ float limp[E_];

  int tid = threadIdx.x, lane = tid & 63, w = tid >> 6;
  int t0 = blockIdx.x * 128;
  int b = t0 >> 11;

  if (tid < E_) {
    float s = br[tid];
    #pragma unroll
    for (int dt = 0; dt < DT_; ++dt) s += z[b * DT_ + dt] * Wr[(D_ + dt) * E_ + tid];
    zlog[tid] = s;
    lcnt[tid] = 0; limp[tid] = 0.f;
  }
  if (tid == 0) stau = TEMP_ * tau[b];

  float wreg[8][8];
  const float* wp = Wr + lane * 64;
  #pragma unroll
  for (int j = 0; j < 8; ++j) {
    f32x4 a = *(const f32x4*)(wp + j * 8);
    f32x4 c = *(const f32x4*)(wp + j * 8 + 4);
    wreg[j][0]=a[0]; wreg[j][1]=a[1]; wreg[j][2]=a[2]; wreg[j][3]=a[3];
    wreg[j][4]=c[0]; wreg[j][5]=c[1]; wreg[j][6]=c[2]; wreg[j][7]=c[3];
  }
  __syncthreads();
  float tv = stau;
  float imp[E_];
  #pragma unroll
  for (int e2 = 0; e2 < E_; ++e2) imp[e2] = 0.f;

  for (int i = 0; i < 32; ++i) {
    int li = w * 32 + i;
    int t = t0 + li;
    const float* xr = x + (size_t)t * D_ + lane * 8;
    f32x4 xa = *(const f32x4*)xr;
    f32x4 xb = *(const f32x4*)(xr + 4);
    float v[E_];
    #pragma unroll
    for (int e2 = 0; e2 < E_; ++e2)
      v[e2] = xa[0]*wreg[0][e2] + xa[1]*wreg[1][e2] + xa[2]*wreg[2][e2] + xa[3]*wreg[3][e2]
            + xb[0]*wreg[4][e2] + xb[1]*wreg[5][e2] + xb[2]*wreg[6][e2] + xb[3]*wreg[7][e2];
    #pragma unroll
    for (int s = 0; s < 6; ++s) {
      #pragma unroll
      for (int e2 = 0; e2 < E_; ++e2) v[e2] += __shfl_xor(v[e2], 1 << s, 64);
    }
    if (lane == 0) {
      #pragma unroll
      for (int e2 = 0; e2 < E_; ++e2) v[e2] = (v[e2] + zlog[e2]) / tv;
      int i0 = 0; float b0v = v[0];
      #pragma unroll
      for (int e2 = 1; e2 < E_; ++e2) if (v[e2] > b0v) { b0v = v[e2]; i0 = e2; }
      int i1 = -1; float b1v = -3.4e38f;
      #pragma unroll
      for (int e2 = 0; e2 < E_; ++e2) if (e2 != i0 && v[e2] > b1v) { b1v = v[e2]; i1 = e2; }
      float ee = expf(b1v - b0v);
      float g0 = 1.f / (1.f + ee);
      recI[li] = i0 | (i1 << 4);
      rg0[li] = g0; rg1[li] = ee * g0;
      float ssum = 0.f, pe[E_];
      #pragma unroll
      for (int e2 = 0; e2 < E_; ++e2) { pe[e2] = expf(v[e2] - b0v); ssum += pe[e2]; }
      float inv = 1.f / ssum;
      #pragma unroll
      for (int e2 = 0; e2 < E_; ++e2) imp[e2] += pe[e2] * inv;
    }
  }
  if (lane == 0) {
    #pragma unroll
    for (int e2 = 0; e2 < E_; ++e2) atomicAdd(&limp[e2], imp[e2]);
  }
  __syncthreads();
  if (tid < 128) {
    int r = recI[tid], i0 = r & 15, i1 = r >> 4;
    pos0[tid] = atomicAdd(&lcnt[i0], 1);
    pos1[tid] = atomicAdd(&lcnt[i1], 1);
  }
  __syncthreads();
  if (tid < E_) {
    lbase[tid] = atomicAdd(&gcnt[tid], lcnt[tid]);
    atomicAdd(&gimp[tid], limp[tid]);
  }
  __syncthreads();
  if (tid < 128) {
    int r = recI[tid], i0 = r & 15, i1 = r >> 4;
    int t = t0 + tid;
    int o0 = i0 * TOKENS + lbase[i0] + pos0[tid];
    int o1 = i1 * TOKENS + lbase[i1] + pos1[tid];
    tokrec[o0] = t; gaterec[o0] = rg0[tid];
    tokrec[o1] = t; gaterec[o1] = rg1[tid];
    slot0[t] = o0; slot1[t] = o1;   // token -> its two segmented slots
  }
}

// exclusive scan of the 8 expert counts (maps segmented slots -> compact rec rows)
__global__ void k_scan(const int* __restrict__ gcnt, int* __restrict__ sbase)
{
  if (threadIdx.x == 0) {
    int a = 0;
    for (int e2 = 0; e2 < E_; ++e2) { sbase[e2] = a; a += gcnt[e2]; }
  }
}

// ---------------------------------------------------------------------------
// Fused expert MLP. XCD-pinned expert (blockIdx&7). Packed fragment-order
// weights -> every weight load is a contiguous 1KB wave burst. Epilogue:
// if use_rec, store g*(acc+b2) rows as f16 records (coalesced via LDS
// transpose-assist); else fall back to f32 atomics.
// ---------------------------------------------------------------------------
__global__ __launch_bounds__(512, 4) void k_mlp(
    const float* __restrict__ x,
    const f16* __restrict__ W1p, const float* __restrict__ b1,
    const f16* __restrict__ W2p, const float* __restrict__ b2,
    const int* __restrict__ gcnt, const int* __restrict__ sbase,
    const int* __restrict__ tokrec, const float* __restrict__ gaterec,
    f16* __restrict__ rec, float* __restrict__ y, int use_rec)
{
  int e    = blockIdx.x & 7;       // XCD pin
  int tile = blockIdx.x >> 3;
  int cnt  = gcnt[e];
  int start = tile * 64;
  if (start >= cnt) return;

  __shared__ f16   xs[64 * 512];   // 64 KB, XOR-swizzled
  __shared__ f16   hs[64 * 64];    // 8 KB, XOR-swizzled
  __shared__ int   stok[64];
  __shared__ float sgate[64];

  int tid = threadIdx.x, lane = tid & 63, w = tid >> 6;

  if (tid < 64) {
    int idx = start + tid;
    stok[tid]  = (idx < cnt) ? tokrec[e * TOKENS + idx] : -1;
    sgate[tid] = (idx < cnt) ? gaterec[e * TOKENS + idx] : 0.f;
  }
  __syncthreads();

  // gather + convert x rows into LDS
  for (int r = w; r < 64; r += 8) {
    int tk = stok[r];
    f32x4 a = {0.f,0.f,0.f,0.f}, bv = {0.f,0.f,0.f,0.f};
    if (tk >= 0) {
      const float* p = x + (size_t)tk * D_ + lane * 8;
      a  = *(const f32x4*)p;
      bv = *(const f32x4*)(p + 4);
    }
    f16x8 pk;
    pk[0]=(f16)a[0];  pk[1]=(f16)a[1];  pk[2]=(f16)a[2];  pk[3]=(f16)a[3];
    pk[4]=(f16)bv[0]; pk[5]=(f16)bv[1]; pk[6]=(f16)bv[2]; pk[7]=(f16)bv[3];
    int off = (r * 1024 + lane * 16) ^ ((r & 7) << 4);
    *(f16x8*)((char*)xs + off) = pk;
  }
  __syncthreads();

  f32x4 yacc[4][4];
  #pragma unroll
  for (int mt = 0; mt < 4; ++mt)
    #pragma unroll
    for (int nt = 0; nt < 4; ++nt) {
      yacc[mt][nt][0]=0.f; yacc[mt][nt][1]=0.f; yacc[mt][nt][2]=0.f; yacc[mt][nt][3]=0.f;
    }

  int rb  = (w & 3) * 16;    // stage-A token-row base
  int cbA = (w >> 2) * 32;   // stage-A F-col base within chunk
  int cb2 = w * 64;          // stage-B D-col base
  int l15 = lane & 15;
  int lk8 = (lane >> 4) * 8;
  // packed bases: frag(ct,ks) at base + (ct*KT + ks)*512 + lane*8
  const f16* w1b = W1p + (size_t)e * 64 * 16 * 512;   // 64 coltiles x 16 ksteps
  const f16* w2b = W2p + (size_t)e * 32 * 32 * 512;   // 32 coltiles x 32 ksteps

  for (int it = 0; it < 16; ++it) {
    int fc = it * 64;
    float b1v0 = b1[e * F_ + fc + cbA + l15];
    float b1v1 = b1[e * F_ + fc + cbA + 16 + l15];

    // ---- stage A: H[64 x 64] = x_tile @ W1-chunk ----
    f32x4 h0 = {0.f,0.f,0.f,0.f}, h1 = {0.f,0.f,0.f,0.f};
    int ct0 = it * 4 + (w >> 2) * 2;          // this wave's two F-coltiles
    const f16* p0 = w1b + ((size_t)ct0 * 16) * 512 + lane * 8;
    const f16* p1 = p0 + 16 * 512;
    #pragma unroll
    for (int kg = 0; kg < 4; ++kg) {
      f16x8 wb[8];
      #pragma unroll
      for (int j = 0; j < 4; ++j) {
        int ks = kg * 4 + j;
        wb[j]     = *(const f16x8*)(p0 + (size_t)ks * 512);
        wb[j + 4] = *(const f16x8*)(p1 + (size_t)ks * 512);
      }
      #pragma unroll
      for (int j = 0; j < 4; ++j) {
        int k0 = (kg * 4 + j) * 32 + lk8;
        int arow = rb + l15;
        int aoff = (arow * 1024 + k0 * 2) ^ ((arow & 7) << 4);
        f16x8 af = *(const f16x8*)((const char*)xs + aoff);
        h0 = __builtin_amdgcn_mfma_f32_16x16x32_f16(af, wb[j],     h0, 0, 0, 0);
        h1 = __builtin_amdgcn_mfma_f32_16x16x32_f16(af, wb[j + 4], h1, 0, 0, 0);
      }
    }
    __syncthreads();   // everyone done reading hs from previous iter
    {
      #pragma unroll
      for (int rg = 0; rg < 4; ++rg) {
        int row = rb + ((lane >> 4) << 2) + rg;
        float v0 = h0[rg] + b1v0;
        float v1 = h1[rg] + b1v1;
        v0 = 0.5f * v0 * (1.f + erff(v0 * 0.70710678118654752f));
        v1 = 0.5f * v1 * (1.f + erff(v1 * 0.70710678118654752f));
        int o0 = (row * 128 + (cbA + l15) * 2)      ^ ((row & 7) << 4);
        int o1 = (row * 128 + (cbA + 16 + l15) * 2) ^ ((row & 7) << 4);
        *(f16*)((char*)hs + o0) = (f16)v0;
        *(f16*)((char*)hs + o1) = (f16)v1;
      }
    }
    __syncthreads();   // hs ready
    // ---- stage B: yacc += H @ W2-chunk ----
    f16x8 wb2[8];
    #pragma unroll
    for (int ks = 0; ks < 2; ++ks)
      #pragma unroll
      for (int nt = 0; nt < 4; ++nt) {
        int ct2 = w * 4 + nt;                 // D-coltile
        int ks2 = it * 2 + ks;                // F-kstep
        wb2[ks * 4 + nt] = *(const f16x8*)(w2b + ((size_t)ct2 * 32 + ks2) * 512 + lane * 8);
      }
    #pragma unroll
    for (int ks = 0; ks < 2; ++ks) {
      int k0 = ks * 32 + lk8;
      f16x8 afr[4];
      #pragma unroll
      for (int mt = 0; mt < 4; ++mt) {
        int arow = mt * 16 + l15;
        int aoff = (arow * 128 + k0 * 2) ^ ((arow & 7) << 4);
        afr[mt] = *(const f16x8*)((const char*)hs + aoff);
      }
      #pragma unroll
      for (int nt = 0; nt < 4; ++nt) {
        #pragma unroll
        for (int mt = 0; mt < 4; ++mt)
          yacc[mt][nt] = __builtin_amdgcn_mfma_f32_16x16x32_f16(afr[mt], wb2[ks * 4 + nt], yacc[mt][nt], 0, 0, 0);
      }
    }
  }

  float b2s[4];
  #pragma unroll
  for (int nt = 0; nt < 4; ++nt) b2s[nt] = b2[e * D_ + cb2 + nt * 16 + l15];

  if (use_rec) {
    // phase 1: gated f16 rows into xs (own-wave stage-B done; xs unused by others now)
    #pragma unroll
    for (int mt = 0; mt < 4; ++mt) {
      #pragma unroll
      for (int rg = 0; rg < 4; ++rg) {
        int row = mt * 16 + ((lane >> 4) << 2) + rg;
        float g = sgate[row];
        #pragma unroll
        for (int nt = 0; nt < 4; ++nt) {
          int col = cb2 + nt * 16 + l15;
          int off = (row * 1024 + col * 2) ^ ((row & 7) << 4);
          *(f16*)((char*)xs + off) = (f16)(g * (yacc[mt][nt][rg] + b2s[nt]));
        }
      }
    }
    __syncthreads();
    // phase 2: coalesced 1KB row stores to rec
    int rbase = sbase[e] + start;
    for (int rr = 0; rr < 8; ++rr) {
      int row = w * 8 + rr;
      if (start + row >= cnt) continue;
      int off = (row * 1024 + lane * 16) ^ ((row & 7) << 4);
      f16x8 v = *(const f16x8*)((const char*)xs + off);
      *(f16x8*)(rec + (size_t)(rbase + row) * 512 + lane * 8) = v;
    }
  } else {
    #pragma unroll
    for (int mt = 0; mt < 4; ++mt) {
      #pragma unroll
      for (int rg = 0; rg < 4; ++rg) {
        int row = mt * 16 + ((lane >> 4) << 2) + rg;
        int tk = stok[row];
        if (tk < 0) continue;
        float g = sgate[row];
        float* yp = y + (size_t)tk * D_ + cb2 + l15;
        #pragma unroll
        for (int nt = 0; nt < 4; ++nt)
          atomicAdd(yp + nt * 16, g * (yacc[mt][nt][rg] + b2s[nt]));
      }
    }
  }
}

// ---------------------------------------------------------------------------
// y[t] = rec[slot0(t)] + rec[slot1(t)]  (gates & b2 already folded into rec)
// ---------------------------------------------------------------------------
__global__ __launch_bounds__(256) void k_combine(
    const f16* __restrict__ rec, const int* __restrict__ slot0,
    const int* __restrict__ slot1, const int* __restrict__ sbase,
    float* __restrict__ y)
{
  int lane = threadIdx.x & 63;
  int wid = (blockIdx.x * 256 + threadIdx.x) >> 6;
  int nw = (gridDim.x * 256) >> 6;
  for (int t = wid; t < TOKENS; t += nw) {
    int o0 = slot0[t], o1 = slot1[t];
    const f16* r0 = rec + ((size_t)sbase[o0 >> 16] + (o0 & 65535)) * 512 + lane * 8;
    const f16* r1 = rec + ((size_t)sbase[o1 >> 16] + (o1 & 65535)) * 512 + lane * 8;
    f16x8 a = *(const f16x8*)r0;
    f16x8 b = *(const f16x8*)r1;
    f32x4 lo, hi;
    lo[0]=(float)a[0]+(float)b[0]; lo[1]=(float)a[1]+(float)b[1];
    lo[2]=(float)a[2]+(float)b[2]; lo[3]=(float)a[3]+(float)b[3];
    hi[0]=(float)a[4]+(float)b[4]; hi[1]=(float)a[5]+(float)b[5];
    hi[2]=(float)a[6]+(float)b[6]; hi[3]=(float)a[7]+(float)b[7];
    float* yp = y + (size_t)t * 512 + lane * 8;
    *(f32x4*)yp = lo;
    *(f32x4*)(yp + 4) = hi;
  }
}

// ---------------------------------------------------------------------------
__global__ void k_aux(const int* __restrict__ gcnt, const float* __restrict__ gimp,
                      float* __restrict__ outp)
{
  if (threadIdx.x == 0) {
    float a = 0.f;
    for (int e2 = 0; e2 < E_; ++e2)
      a += ((float)gcnt[e2] * (1.f / 65536.f)) * (gimp[e2] * (1.f / 65536.f));
    outp[0] = (float)E_ * a;
  }
}

extern "C" void kernel_launch(void* const* d_in, const int* in_sizes, int n_in,
                              void* d_out, int out_size, void* d_ws, size_t ws_size,
                              hipStream_t stream)
{
  const float* x   = (const float*)d_in[0];
  const float* z   = (const float*)d_in[1];
  const float* tau = (const float*)d_in[2];
  const float* Wr  = (const float*)d_in[3];
  const float* br  = (const float*)d_in[4];
  const float* W1  = (const float*)d_in[5];
  const float* b1  = (const float*)d_in[6];
  const float* W2  = (const float*)d_in[7];
  const float* b2  = (const float*)d_in[8];
  float* out = (float*)d_out;
  char*  ws  = (char*)d_ws;

  int*   gcnt    = (int*)  (ws + OFF_CNT);
  int*   sbase   = (int*)  (ws + OFF_SBASE);
  float* gimp    = (float*)(ws + OFF_IMP);
  int*   slot0   = (int*)  (ws + OFF_SLOT0);
  int*   slot1   = (int*)  (ws + OFF_SLOT1);
  int*   tokrec  = (int*)  (ws + OFF_TOK);
  float* gaterec = (float*)(ws + OFF_GATE);
  f16*   W1p     = (f16*)  (ws + OFF_W1P);
  f16*   W2p     = (f16*)  (ws + OFF_W2P);
  f16*   rec     = (f16*)  (ws + OFF_REC);

  int use_rec = (ws_size >= (size_t)OFF_REC + REC_BYTES) ? 1 : 0;

  hipMemsetAsync(ws, 0, 4096, stream);                        // counters
  if (!use_rec)
    hipMemsetAsync(d_out, 0, (size_t)out_size * 4, stream);   // y accumulators

  k_pack<<<dim3(F_/16, E_), 256, 0, stream>>>(W1, W1p, D_, F_); // R=D(K), C=F(N)
  k_pack<<<dim3(D_/16, E_), 256, 0, stream>>>(W2, W2p, F_, D_); // R=F(K), C=D(N)

  k_router<<<TOKENS / 128, 256, 0, stream>>>(x, z, tau, Wr, br, gcnt, gimp,
                                             tokrec, gaterec, slot0, slot1);
  k_scan<<<1, 64, 0, stream>>>(gcnt, sbase);

  k_mlp<<<E_ * 1024, 512, 0, stream>>>(x, W1p, b1, W2p, b2, gcnt, sbase,
                                       tokrec, gaterec, rec, out, use_rec);

  if (use_rec)
    k_combine<<<2048, 256, 0, stream>>>(rec, slot0, slot1, sbase, out);

  k_aux<<<1, 64, 0, stream>>>(gcnt, gimp, out + (size_t)TOKENS * D_);
}